// Round 3
// baseline (11318.184 us; speedup 1.0000x reference)
//
#include <hip/hip_runtime.h>
#include <stdint.h>

// Sizes (fixed per reference): B=128, T=256, N=256, M=256
#define NB 128

typedef _Float16 f16;
typedef _Float16 f16x2 __attribute__((ext_vector_type(2)));

// ---------------- workspace layout (bytes) ----------------
#define WS_PREX   0u            // f16 [128][256][256]  (KC * pre_x[b][n][t'])
#define WS_WUT    16777216u     // uint4[16][1024]: chunk for (d8,t') at pos i*1024 + t'*4 + tq, i=d8&15, tq=d8>>4
#define WS_WCAT   17039360u     // uint4[64][1024]: f16-pairs of concat(W_ih,W_hh)[j][k], chunk (k8,j) at k8*1024+j
#define WS_WXT    18087936u     // f32 [256][256]     WxT[t][t'] = WU_e[t'][512+t]
#define WS_END    18350080u

__device__ __forceinline__ float fast_exp2(float x) {
#if __has_builtin(__builtin_amdgcn_exp2f)
  return __builtin_amdgcn_exp2f(x);
#else
  return exp2f(x);
#endif
}
__device__ __forceinline__ float fast_rcp(float x) {
#if __has_builtin(__builtin_amdgcn_rcpf)
  return __builtin_amdgcn_rcpf(x);
#else
  return 1.0f / x;
#endif
}

__device__ __forceinline__ float fdot2(uint32_t w, uint32_t x, float acc) {
#if __has_builtin(__builtin_amdgcn_fdot2)
  return __builtin_amdgcn_fdot2(__builtin_bit_cast(f16x2, w),
                                __builtin_bit_cast(f16x2, x), acc, false);
#else
  f16x2 a = __builtin_bit_cast(f16x2, w);
  f16x2 b = __builtin_bit_cast(f16x2, x);
  acc = fmaf((float)a.x, (float)b.x, acc);
  acc = fmaf((float)a.y, (float)b.y, acc);
  return acc;
#endif
}

__device__ __forceinline__ uint32_t pack2(float lo, float hi) {
#if __has_builtin(__builtin_amdgcn_cvt_pkrtz)
  return __builtin_bit_cast(uint32_t, __builtin_amdgcn_cvt_pkrtz(lo, hi));
#else
  f16x2 p; p.x = (f16)lo; p.y = (f16)hi;
  return __builtin_bit_cast(uint32_t, p);
#endif
}

// Raw barrier: LDS visibility only (lgkmcnt(0)); global register loads keep
// flying across it (compiler emits counted vmcnt at the consumer). This is
// the whole point of this round — __syncthreads() would drain vmcnt(0).
__device__ __forceinline__ void lds_barrier() {
  asm volatile("s_waitcnt lgkmcnt(0)" ::: "memory");
  __builtin_amdgcn_s_barrier();
}

#define KCONST 2.8853900817779268f  // 2*log2(e)
#define KLOG2E 1.4426950408889634f  // log2(e)

// ---------------- K0: pack/transpose weights ----------------
__global__ __launch_bounds__(256) void prep_pack(const float* __restrict__ WU_e,
                                                 const float* __restrict__ W_ih,
                                                 const float* __restrict__ W_hh,
                                                 uint8_t* __restrict__ ws) {
  float* wxt = (float*)(ws + WS_WXT);
  uint32_t* wut = (uint32_t*)(ws + WS_WUT);
  uint32_t* wcat = (uint32_t*)(ws + WS_WCAT);
  int idx = blockIdx.x * blockDim.x + threadIdx.x;
  if (idx < 65536) {
    int t = idx >> 8, t2 = idx & 255;
    wxt[t * 256 + t2] = WU_e[t2 * 768 + 512 + t];
  } else if (idx < 65536 + 16384) {
    int i2 = idx - 65536;
    int d8 = i2 >> 8, tp = i2 & 255;
    int ii = d8 & 15, tq = d8 >> 4;
    uint32_t* dst = wut + (ii * 1024 + tp * 4 + tq) * 4;
#pragma unroll
    for (int w = 0; w < 4; ++w) {
      int d = d8 * 8 + 2 * w;
      f16x2 p;
      p.x = (f16)WU_e[tp * 768 + d];
      p.y = (f16)WU_e[tp * 768 + d + 1];
      dst[w] = __builtin_bit_cast(uint32_t, p);
    }
  } else if (idx < 65536 + 16384 + 65536) {
    int i2 = idx - (65536 + 16384);
    int k8 = i2 >> 10, j = i2 & 1023;
    uint32_t* dst = wcat + (k8 * 1024 + j) * 4;
#pragma unroll
    for (int w = 0; w < 4; ++w) {
      int k0 = k8 * 8 + 2 * w;
      int k1 = k0 + 1;
      float a = (k0 < 256) ? W_ih[j * 256 + k0] : W_hh[j * 256 + (k0 - 256)];
      float b = (k1 < 256) ? W_ih[j * 256 + k1] : W_hh[j * 256 + (k1 - 256)];
      f16x2 p; p.x = (f16)a; p.y = (f16)b;
      dst[w] = __builtin_bit_cast(uint32_t, p);
    }
  }
}

// ---------------- K1: pre_x[b][n][t'] = KC * sum_t X[b][t][n] * WxT[t][t'] ----------------
__global__ __launch_bounds__(512) void prep_prex(const float* __restrict__ X,
                                                 uint8_t* __restrict__ ws) {
  __shared__ float Xs[32][128];
  __shared__ float Wt[32][256];
  const float* wxt = (const float*)(ws + WS_WXT);
  f16* prex = (f16*)(ws + WS_PREX);
  const int b = blockIdx.x >> 1;
  const int n0 = (blockIdx.x & 1) * 128;
  const int tid = threadIdx.x;
  const int tt = tid & 31;
  const int tn = tid >> 5;
  float acc[8][8];
#pragma unroll
  for (int i = 0; i < 8; ++i)
#pragma unroll
    for (int j = 0; j < 8; ++j) acc[i][j] = 0.f;

  for (int tc = 0; tc < 8; ++tc) {
#pragma unroll
    for (int it = 0; it < 8; ++it) {
      int idx = tid + it * 512;
      int tr = idx >> 7, nc = idx & 127;
      Xs[tr][nc] = X[((b * 256) + tc * 32 + tr) * 256 + n0 + nc];
    }
#pragma unroll
    for (int it = 0; it < 16; ++it) {
      int idx = tid + it * 512;
      int tr = idx >> 8, c = idx & 255;
      Wt[tr][c] = wxt[(tc * 32 + tr) * 256 + c];
    }
    __syncthreads();
    for (int tr = 0; tr < 32; ++tr) {
      float xa[8], wb[8];
#pragma unroll
      for (int i = 0; i < 8; ++i) xa[i] = Xs[tr][tn * 8 + i];
#pragma unroll
      for (int j = 0; j < 8; ++j) wb[j] = Wt[tr][tt * 8 + j];
#pragma unroll
      for (int i = 0; i < 8; ++i)
#pragma unroll
        for (int j = 0; j < 8; ++j) acc[i][j] = fmaf(xa[i], wb[j], acc[i][j]);
    }
    __syncthreads();
  }
#pragma unroll
  for (int i = 0; i < 8; ++i) {
    int n = n0 + tn * 8 + i;
    uint32_t o[4];
#pragma unroll
    for (int u = 0; u < 4; ++u)
      o[u] = pack2(KCONST * acc[i][2 * u], KCONST * acc[i][2 * u + 1]);
    *(uint4*)(prex + (size_t)b * 65536 + n * 256 + tt * 8) = make_uint4(o[0], o[1], o[2], o[3]);
  }
}

// ---------------- K2: persistent recurrence, 1 block per batch element ----------------
// LDS layout (bytes):
#define L_PX    0u       // f16 [256][256] unpadded (512B rows), KC-prescaled
#define L_HSPK  131072u  // u32[256]: f16x2 pairs of [h(128 pairs), c(128 pairs)]
#define L_XHPK  132096u  // u32[256]: f16x2 pairs of [x_tilde(128), h(128)]
#define L_KEH   133120u  // f32[256]: KC * e_pre_h[t']
#define L_WB    134144u  // f32[256]: w = exp(e[n])
#define L_GB    135168u  // f32[1024]: gates
#define LDS_TOTAL 139264u

#define PFD 12  // wcat register-prefetch depth (uint4 x12 = 48 VGPRs)

__global__ __launch_bounds__(1024) void encoder_run(
    const float* __restrict__ X, const float* __restrict__ v_e,
    const float* __restrict__ b_ih, const float* __restrict__ b_hh,
    const uint8_t* __restrict__ ws, float* __restrict__ out) {
  extern __shared__ uint8_t lds[];
  uint32_t* hs_pk = (uint32_t*)(lds + L_HSPK);
  uint32_t* xh_pk = (uint32_t*)(lds + L_XHPK);
  float* keh  = (float*)(lds + L_KEH);
  float* wbuf = (float*)(lds + L_WB);
  float* gbuf = (float*)(lds + L_GB);

  const int b = blockIdx.x;
  const int tid = threadIdx.x;
  const uint4* wut_v  = (const uint4*)(ws + WS_WUT);
  const uint4* wcat_v = (const uint4*)(ws + WS_WCAT);
  const uint32_t* prex_g = (const uint32_t*)(ws + WS_PREX) + (size_t)b * 32768u;

  const int tq  = tid & 3;        // Phase A: K-quarter
  const int thi = tid >> 2;       // Phase A: t'
  const int li  = tid & 31;       // Phase B: 16B chunk within row
  const int half = (tid >> 5) & 1;
  const int wbase = (tid >> 6) * 16;  // Phase B: first row of this wave

  // ---- init ----
  if (tid < 256) { hs_pk[tid] = 0u; xh_pk[tid] = 0u; }
  float creg = 0.f;
  float bsum_r = b_ih[tid] + b_hh[tid];
#pragma unroll
  for (int it = 0; it < 8; ++it) {   // copy KC*pre_x[b] into LDS, 8192 x 16B contiguous
    int c = tid + it * 1024;
    uint4 v = *(const uint4*)(prex_g + c * 4);
    *(uint4*)(lds + (size_t)c * 16) = v;
  }
  float m2ve[8], ve_ssum = 0.f;
  {
    float4 v0 = *(const float4*)(v_e + li * 8);
    float4 v1 = *(const float4*)(v_e + li * 8 + 4);
    float vv[8] = {v0.x, v0.y, v0.z, v0.w, v1.x, v1.y, v1.z, v1.w};
#pragma unroll
    for (int j = 0; j < 8; ++j) { m2ve[j] = -2.f * vv[j]; ve_ssum += vv[j]; }
  }
  __syncthreads();   // init: full drain is fine (once)

  for (int t = 0; t < 256; ++t) {
    // ---- top-of-step issue: X row, then wut depth 4 ----
    float xv_pre = 0.f;
    if (tid < 256) xv_pre = X[(((size_t)b << 8) + (size_t)t) * 256 + tid];
    uint4 pfa[4];
#pragma unroll
    for (int p = 0; p < 4; ++p) pfa[p] = wut_v[p * 1024 + tid];

    // ---- Phase A: keh[t'] = KC * sum_d hs[d]*WU_e[t'][d] (fdot2) ----
    {
      float a = 0.f;
#pragma unroll
      for (int i = 0; i < 16; ++i) {
        uint4 wv = pfa[i & 3];
        if (i < 12) pfa[i & 3] = wut_v[(i + 4) * 1024 + tid];
        uint4 hv = *(const uint4*)(hs_pk + (tq * 16 + i) * 4);
        a = fdot2(wv.x, hv.x, a);
        a = fdot2(wv.y, hv.y, a);
        a = fdot2(wv.z, hv.z, a);
        a = fdot2(wv.w, hv.w, a);
      }
      a += __shfl_xor(a, 1);
      a += __shfl_xor(a, 2);
      if (tq == 0) keh[thi] = KCONST * a;
    }

    // ---- issue wcat prefetch burst (streams during Phase B/C windows) ----
    uint4 pf[PFD];
#pragma unroll
    for (int p = 0; p < PFD; ++p) pf[p] = wcat_v[p * 1024 + tid];

    lds_barrier();

    // ---- Phase B: e[n] = sum_t' ve[t']*tanh(px + eh); wbuf[n] = exp(e[n]) ----
    {
      float kr[8];
      {
        float4 k0 = *(const float4*)(keh + li * 8);
        float4 k1 = *(const float4*)(keh + li * 8 + 4);
        kr[0]=k0.x; kr[1]=k0.y; kr[2]=k0.z; kr[3]=k0.w;
        kr[4]=k1.x; kr[5]=k1.y; kr[6]=k1.z; kr[7]=k1.w;
      }
#pragma unroll
      for (int i = 0; i < 8; ++i) {
        int r = wbase + i * 2 + half;
        uint4 pv = *(const uint4*)(lds + (size_t)r * 512 + (size_t)li * 16);
        float acc = ve_ssum;
        uint32_t dw[4] = {pv.x, pv.y, pv.z, pv.w};
#pragma unroll
        for (int u = 0; u < 4; ++u) {
          f16x2 q = __builtin_bit_cast(f16x2, dw[u]);
          {
            float y = (float)q.x + kr[2 * u];
            acc = fmaf(m2ve[2 * u], fast_rcp(fast_exp2(y) + 1.f), acc);
          }
          {
            float y = (float)q.y + kr[2 * u + 1];
            acc = fmaf(m2ve[2 * u + 1], fast_rcp(fast_exp2(y) + 1.f), acc);
          }
        }
        acc += __shfl_xor(acc, 1);
        acc += __shfl_xor(acc, 2);
        acc += __shfl_xor(acc, 4);
        acc += __shfl_xor(acc, 8);
        acc += __shfl_xor(acc, 16);
        if (li == 0) wbuf[r] = fast_exp2(KLOG2E * acc);
      }
    }
    lds_barrier();

    // ---- Phase C: softmax denom + x_tilde (waves 0-3), pack f16 pairs ----
    if (tid < 256) {
      int lane = tid & 63;
      float4 wv = *(const float4*)(wbuf + lane * 4);
      float s = (wv.x + wv.y) + (wv.z + wv.w);
      s += __shfl_xor(s, 1);  s += __shfl_xor(s, 2);  s += __shfl_xor(s, 4);
      s += __shfl_xor(s, 8);  s += __shfl_xor(s, 16); s += __shfl_xor(s, 32);
      float xt = xv_pre * wbuf[tid] * fast_rcp(s);
      float xo = __shfl_xor(xt, 1);
      if (!(tid & 1)) xh_pk[tid >> 1] = pack2(xt, xo);
    }
    lds_barrier();

    // ---- Phase E: gates[j] = bsum[j] + sum_k [x_tilde,h][k]*Wcat[j][k] (fdot2) ----
    {
      float a0 = bsum_r, a1 = 0.f, a2 = 0.f, a3 = 0.f;
#pragma unroll
      for (int k8 = 0; k8 < 64; ++k8) {
        uint4 wv = pf[k8 % PFD];
        if (k8 < 64 - PFD) pf[k8 % PFD] = wcat_v[(k8 + PFD) * 1024 + tid];
        uint4 xv4 = *(const uint4*)(xh_pk + k8 * 4);
        a0 = fdot2(wv.x, xv4.x, a0);
        a1 = fdot2(wv.y, xv4.y, a1);
        a2 = fdot2(wv.z, xv4.z, a2);
        a3 = fdot2(wv.w, xv4.w, a3);
      }
      gbuf[tid] = (a0 + a1) + (a2 + a3);
    }
    lds_barrier();

    // ---- Phase F: LSTM cell update + output + pack h,c ----
    if (tid < 256) {
      float gi = gbuf[tid], gf = gbuf[tid + 256], gg = gbuf[tid + 512], go = gbuf[tid + 768];
      float si = fast_rcp(1.f + fast_exp2(-KLOG2E * gi));
      float sf = fast_rcp(1.f + fast_exp2(-KLOG2E * gf));
      float so = fast_rcp(1.f + fast_exp2(-KLOG2E * go));
      float tg = fmaf(-2.f, fast_rcp(1.f + fast_exp2(KCONST * gg)), 1.f);
      float cn = fmaf(sf, creg, si * tg);
      float tc2 = fmaf(-2.f, fast_rcp(1.f + fast_exp2(KCONST * cn)), 1.f);
      float hn = so * tc2;
      creg = cn;
      float hp = __shfl_xor(hn, 1);
      float cp = __shfl_xor(cn, 1);
      if (!(tid & 1)) {
        uint32_t hpk = pack2(hn, hp);
        uint32_t cpk = pack2(cn, cp);
        hs_pk[tid >> 1] = hpk;
        hs_pk[128 + (tid >> 1)] = cpk;
        xh_pk[128 + (tid >> 1)] = hpk;
      }
      out[(((size_t)t << 7) + (size_t)b) * 256 + tid] = hn;  // out[t][b][m]
    }
    lds_barrier();
  }
}

extern "C" void kernel_launch(void* const* d_in, const int* in_sizes, int n_in,
                              void* d_out, int out_size, void* d_ws, size_t ws_size,
                              hipStream_t stream) {
  const float* X    = (const float*)d_in[0];
  const float* WU_e = (const float*)d_in[1];
  const float* v_e  = (const float*)d_in[2];
  const float* W_ih = (const float*)d_in[3];
  const float* W_hh = (const float*)d_in[4];
  const float* b_ih = (const float*)d_in[5];
  const float* b_hh = (const float*)d_in[6];
  uint8_t* ws = (uint8_t*)d_ws;
  float* out = (float*)d_out;

  (void)hipFuncSetAttribute((const void*)encoder_run,
                            hipFuncAttributeMaxDynamicSharedMemorySize,
                            (int)LDS_TOTAL);

  prep_pack<<<576, 256, 0, stream>>>(WU_e, W_ih, W_hh, ws);
  prep_prex<<<256, 512, 0, stream>>>(X, ws);
  encoder_run<<<NB, 1024, LDS_TOTAL, stream>>>(X, v_e, b_ih, b_hh, ws, out);
}

// Round 4
// 10305.966 us; speedup vs baseline: 1.0982x; 1.0982x over previous
//
#include <hip/hip_runtime.h>
#include <stdint.h>

// Sizes (fixed per reference): B=128, T=256, N=256, M=256
#define NB 128

typedef _Float16 f16;
typedef _Float16 f16x2 __attribute__((ext_vector_type(2)));

// ---------------- workspace layout (bytes) ----------------
#define WS_PREX   0u            // f16 [128][256][256]  (KC * pre_x[b][n][t'])
#define WS_WUT    16777216u     // uint4[16][1024]: chunk for (d8,t') at i*1024 + t'*4 + tq, i=d8&15, tq=d8>>4
#define WS_WCAT   17039360u     // uint4[64][1024]: f16-pairs of concat(W_ih,W_hh)[j][k], chunk (k8,j) at k8*1024+j
#define WS_WXT    18087936u     // f32 [256][256]     WxT[t][t'] = WU_e[t'][512+t]
#define WS_END    18350080u

__device__ __forceinline__ float fast_exp2(float x) {
#if __has_builtin(__builtin_amdgcn_exp2f)
  return __builtin_amdgcn_exp2f(x);
#else
  return exp2f(x);
#endif
}
__device__ __forceinline__ float fast_rcp(float x) {
#if __has_builtin(__builtin_amdgcn_rcpf)
  return __builtin_amdgcn_rcpf(x);
#else
  return 1.0f / x;
#endif
}

__device__ __forceinline__ float fdot2(uint32_t w, uint32_t x, float acc) {
#if __has_builtin(__builtin_amdgcn_fdot2)
  return __builtin_amdgcn_fdot2(__builtin_bit_cast(f16x2, w),
                                __builtin_bit_cast(f16x2, x), acc, false);
#else
  f16x2 a = __builtin_bit_cast(f16x2, w);
  f16x2 b = __builtin_bit_cast(f16x2, x);
  acc = fmaf((float)a.x, (float)b.x, acc);
  acc = fmaf((float)a.y, (float)b.y, acc);
  return acc;
#endif
}

__device__ __forceinline__ uint32_t pack2(float lo, float hi) {
#if __has_builtin(__builtin_amdgcn_cvt_pkrtz)
  return __builtin_bit_cast(uint32_t, __builtin_amdgcn_cvt_pkrtz(lo, hi));
#else
  f16x2 p; p.x = (f16)lo; p.y = (f16)hi;
  return __builtin_bit_cast(uint32_t, p);
#endif
}

// LDS-only barrier: drains LDS ops, leaves global loads in flight (counted
// vmcnt waits are emitted at each pinned consume site instead).
__device__ __forceinline__ void lds_barrier() {
  asm volatile("s_waitcnt lgkmcnt(0)" ::: "memory");
  __builtin_amdgcn_s_barrier();
}

// Force a loaded uint4 to materialize in VGPRs HERE. This makes the compiler
// (a) keep the load result in registers (no scratch, no sinking to use) and
// (b) emit a counted s_waitcnt vmcnt(N) at this point.
#define PIN4(R) asm volatile("" : "+v"((R).x), "+v"((R).y), "+v"((R).z), "+v"((R).w))

#define KCONST 2.8853900817779268f  // 2*log2(e)
#define KLOG2E 1.4426950408889634f  // log2(e)

// ---------------- K0: pack/transpose weights ----------------
__global__ __launch_bounds__(256) void prep_pack(const float* __restrict__ WU_e,
                                                 const float* __restrict__ W_ih,
                                                 const float* __restrict__ W_hh,
                                                 uint8_t* __restrict__ ws) {
  float* wxt = (float*)(ws + WS_WXT);
  uint32_t* wut = (uint32_t*)(ws + WS_WUT);
  uint32_t* wcat = (uint32_t*)(ws + WS_WCAT);
  int idx = blockIdx.x * blockDim.x + threadIdx.x;
  if (idx < 65536) {
    int t = idx >> 8, t2 = idx & 255;
    wxt[t * 256 + t2] = WU_e[t2 * 768 + 512 + t];
  } else if (idx < 65536 + 16384) {
    int i2 = idx - 65536;
    int d8 = i2 >> 8, tp = i2 & 255;
    int ii = d8 & 15, tq = d8 >> 4;
    uint32_t* dst = wut + (ii * 1024 + tp * 4 + tq) * 4;
#pragma unroll
    for (int w = 0; w < 4; ++w) {
      int d = d8 * 8 + 2 * w;
      f16x2 p;
      p.x = (f16)WU_e[tp * 768 + d];
      p.y = (f16)WU_e[tp * 768 + d + 1];
      dst[w] = __builtin_bit_cast(uint32_t, p);
    }
  } else if (idx < 65536 + 16384 + 65536) {
    int i2 = idx - (65536 + 16384);
    int k8 = i2 >> 10, j = i2 & 1023;
    uint32_t* dst = wcat + (k8 * 1024 + j) * 4;
#pragma unroll
    for (int w = 0; w < 4; ++w) {
      int k0 = k8 * 8 + 2 * w;
      int k1 = k0 + 1;
      float a = (k0 < 256) ? W_ih[j * 256 + k0] : W_hh[j * 256 + (k0 - 256)];
      float b = (k1 < 256) ? W_ih[j * 256 + k1] : W_hh[j * 256 + (k1 - 256)];
      f16x2 p; p.x = (f16)a; p.y = (f16)b;
      dst[w] = __builtin_bit_cast(uint32_t, p);
    }
  }
}

// ---------------- K1: pre_x[b][n][t'] = KC * sum_t X[b][t][n] * WxT[t][t'] ----------------
__global__ __launch_bounds__(512) void prep_prex(const float* __restrict__ X,
                                                 uint8_t* __restrict__ ws) {
  __shared__ float Xs[32][128];
  __shared__ float Wt[32][256];
  const float* wxt = (const float*)(ws + WS_WXT);
  f16* prex = (f16*)(ws + WS_PREX);
  const int b = blockIdx.x >> 1;
  const int n0 = (blockIdx.x & 1) * 128;
  const int tid = threadIdx.x;
  const int tt = tid & 31;
  const int tn = tid >> 5;
  float acc[8][8];
#pragma unroll
  for (int i = 0; i < 8; ++i)
#pragma unroll
    for (int j = 0; j < 8; ++j) acc[i][j] = 0.f;

  for (int tc = 0; tc < 8; ++tc) {
#pragma unroll
    for (int it = 0; it < 8; ++it) {
      int idx = tid + it * 512;
      int tr = idx >> 7, nc = idx & 127;
      Xs[tr][nc] = X[((b * 256) + tc * 32 + tr) * 256 + n0 + nc];
    }
#pragma unroll
    for (int it = 0; it < 16; ++it) {
      int idx = tid + it * 512;
      int tr = idx >> 8, c = idx & 255;
      Wt[tr][c] = wxt[(tc * 32 + tr) * 256 + c];
    }
    __syncthreads();
    for (int tr = 0; tr < 32; ++tr) {
      float xa[8], wb[8];
#pragma unroll
      for (int i = 0; i < 8; ++i) xa[i] = Xs[tr][tn * 8 + i];
#pragma unroll
      for (int j = 0; j < 8; ++j) wb[j] = Wt[tr][tt * 8 + j];
#pragma unroll
      for (int i = 0; i < 8; ++i)
#pragma unroll
        for (int j = 0; j < 8; ++j) acc[i][j] = fmaf(xa[i], wb[j], acc[i][j]);
    }
    __syncthreads();
  }
#pragma unroll
  for (int i = 0; i < 8; ++i) {
    int n = n0 + tn * 8 + i;
    uint32_t o[4];
#pragma unroll
    for (int u = 0; u < 4; ++u)
      o[u] = pack2(KCONST * acc[i][2 * u], KCONST * acc[i][2 * u + 1]);
    *(uint4*)(prex + (size_t)b * 65536 + n * 256 + tt * 8) = make_uint4(o[0], o[1], o[2], o[3]);
  }
}

// ---------------- K2: persistent recurrence, 1 block per batch element ----------------
// LDS layout (bytes):
#define L_PX    0u       // f16 [256][256] unpadded (512B rows), KC-prescaled
#define L_HSPK  131072u  // u32[256]: f16x2 pairs of [h(128 pairs), c(128 pairs)]
#define L_XHPK  132096u  // u32[256]: f16x2 pairs of [x_tilde(128), h(128)]
#define L_KEH   133120u  // f32[288]: KC * e_pre_h, PADDED stride-9 (idx = t' + t'/8)
#define L_WB    134400u  // f32[256]: w = exp(e[n])
#define L_GB    135424u  // f32[1024]: gates
#define LDS_TOTAL 139520u

__global__ __launch_bounds__(1024) void encoder_run(
    const float* __restrict__ X, const float* __restrict__ v_e,
    const float* __restrict__ b_ih, const float* __restrict__ b_hh,
    const uint8_t* __restrict__ ws, float* __restrict__ out) {
  extern __shared__ uint8_t lds[];
  uint32_t* hs_pk = (uint32_t*)(lds + L_HSPK);
  uint32_t* xh_pk = (uint32_t*)(lds + L_XHPK);
  float* keh  = (float*)(lds + L_KEH);
  float* wbuf = (float*)(lds + L_WB);
  float* gbuf = (float*)(lds + L_GB);

  const int b = blockIdx.x;
  const int tid = threadIdx.x;
  const uint4* wut_v  = (const uint4*)(ws + WS_WUT);
  const uint4* wcat_v = (const uint4*)(ws + WS_WCAT);
  const uint32_t* prex_g = (const uint32_t*)(ws + WS_PREX) + (size_t)b * 32768u;

  const int tq  = tid & 3;        // Phase A: K-quarter
  const int thi = tid >> 2;       // Phase A: t'
  const int li  = tid & 31;       // Phase B: 16B chunk within row
  const int half = (tid >> 5) & 1;
  const int wbase = (tid >> 6) * 16;  // Phase B: first row of this wave

  // ---- init ----
  if (tid < 256) { hs_pk[tid] = 0u; xh_pk[tid] = 0u; }
  float creg = 0.f;
  float bsum_r = b_ih[tid] + b_hh[tid];
#pragma unroll
  for (int it = 0; it < 8; ++it) {   // copy KC*pre_x[b] into LDS, 8192 x 16B contiguous
    int c = tid + it * 1024;
    uint4 v = *(const uint4*)(prex_g + c * 4);
    *(uint4*)(lds + (size_t)c * 16) = v;
  }
  float m2ve[8], ve_ssum = 0.f;
  {
    float4 v0 = *(const float4*)(v_e + li * 8);
    float4 v1 = *(const float4*)(v_e + li * 8 + 4);
    float vv[8] = {v0.x, v0.y, v0.z, v0.w, v1.x, v1.y, v1.z, v1.w};
#pragma unroll
    for (int j = 0; j < 8; ++j) { m2ve[j] = -2.f * vv[j]; ve_ssum += vv[j]; }
  }
  __syncthreads();   // init only

// ---- static prefetch helpers ----
#define AISS(R, I)  R = wut_v[(I) * 1024 + tid]
#define ACONS(R, I) { PIN4(R); \
    uint4 hv = *(const uint4*)(hs_pk + ((tq << 4) + (I)) * 4); \
    a = fdot2((R).x, hv.x, a); a = fdot2((R).y, hv.y, a); \
    a = fdot2((R).z, hv.z, a); a = fdot2((R).w, hv.w, a); }
#define EISS(R, K8)  R = wcat_v[(K8) * 1024 + tid]
#define ECONS(R, K8) { PIN4(R); \
    uint4 xv4 = *(const uint4*)(xh_pk + (K8) * 4); \
    a0 = fdot2((R).x, xv4.x, a0); a1 = fdot2((R).y, xv4.y, a1); \
    a2 = fdot2((R).z, xv4.z, a2); a3 = fdot2((R).w, xv4.w, a3); }

  for (int t = 0; t < 256; ++t) {
    // ---- top-of-step: X row + Phase-A chunk issue (16 deep, static regs) ----
    float xv_pre = 0.f;
    if (tid < 256) xv_pre = X[(((size_t)b << 8) + (size_t)t) * 256 + tid];
    uint4 w0, w1, w2, w3, w4, w5, w6, w7, w8, w9, w10, w11, w12, w13, w14, w15;
    AISS(w0, 0);  AISS(w1, 1);  AISS(w2, 2);  AISS(w3, 3);
    AISS(w4, 4);  AISS(w5, 5);  AISS(w6, 6);  AISS(w7, 7);
    AISS(w8, 8);  AISS(w9, 9);  AISS(w10, 10); AISS(w11, 11);
    AISS(w12, 12); AISS(w13, 13); AISS(w14, 14); AISS(w15, 15);
    __builtin_amdgcn_sched_barrier(0);
    // first wcat bank issues early: latency hides under Phase A tail + B + C
    uint4 eA0, eA1, eA2, eA3, eA4, eA5, eA6, eA7;
    EISS(eA0, 0); EISS(eA1, 1); EISS(eA2, 2); EISS(eA3, 3);
    EISS(eA4, 4); EISS(eA5, 5); EISS(eA6, 6); EISS(eA7, 7);
    __builtin_amdgcn_sched_barrier(0);

    // ---- Phase A: keh[t'] = KC * sum_d hs[d]*WU_e[t'][d] (fdot2, pinned) ----
    {
      float a = 0.f;
      ACONS(w0, 0);  ACONS(w1, 1);  ACONS(w2, 2);  ACONS(w3, 3);
      ACONS(w4, 4);  ACONS(w5, 5);  ACONS(w6, 6);  ACONS(w7, 7);
      ACONS(w8, 8);  ACONS(w9, 9);  ACONS(w10, 10); ACONS(w11, 11);
      ACONS(w12, 12); ACONS(w13, 13); ACONS(w14, 14); ACONS(w15, 15);
      a += __shfl_xor(a, 1);
      a += __shfl_xor(a, 2);
      if (tq == 0) keh[thi + (thi >> 3)] = KCONST * a;   // padded stride-9
    }
    // second wcat bank
    uint4 eB0, eB1, eB2, eB3, eB4, eB5, eB6, eB7;
    EISS(eB0, 8);  EISS(eB1, 9);  EISS(eB2, 10); EISS(eB3, 11);
    EISS(eB4, 12); EISS(eB5, 13); EISS(eB6, 14); EISS(eB7, 15);
    __builtin_amdgcn_sched_barrier(0);

    lds_barrier();

    // ---- Phase B: e[n] = sum_t' ve[t']*tanh(px + eh); wbuf[n] = exp(e[n]) ----
    {
      float kr[8];
      {
        const float* kehb = keh + li * 9;   // padded: conflict-free b32 reads
#pragma unroll
        for (int j = 0; j < 8; ++j) kr[j] = kehb[j];
      }
#pragma unroll
      for (int i = 0; i < 8; ++i) {
        int r = wbase + i * 2 + half;
        uint4 pv = *(const uint4*)(lds + (size_t)r * 512 + (size_t)li * 16);
        float acc = ve_ssum;
        uint32_t dw[4] = {pv.x, pv.y, pv.z, pv.w};
#pragma unroll
        for (int u = 0; u < 4; ++u) {
          f16x2 q = __builtin_bit_cast(f16x2, dw[u]);
          {
            float y = (float)q.x + kr[2 * u];
            acc = fmaf(m2ve[2 * u], fast_rcp(fast_exp2(y) + 1.f), acc);
          }
          {
            float y = (float)q.y + kr[2 * u + 1];
            acc = fmaf(m2ve[2 * u + 1], fast_rcp(fast_exp2(y) + 1.f), acc);
          }
        }
        acc += __shfl_xor(acc, 1);
        acc += __shfl_xor(acc, 2);
        acc += __shfl_xor(acc, 4);
        acc += __shfl_xor(acc, 8);
        acc += __shfl_xor(acc, 16);
        if (li == 0) wbuf[r] = fast_exp2(KLOG2E * acc);
      }
    }
    lds_barrier();

    // ---- Phase C: softmax denom + x_tilde (waves 0-3), pack f16 pairs ----
    if (tid < 256) {
      int lane = tid & 63;
      float4 wv = *(const float4*)(wbuf + lane * 4);
      float s = (wv.x + wv.y) + (wv.z + wv.w);
      s += __shfl_xor(s, 1);  s += __shfl_xor(s, 2);  s += __shfl_xor(s, 4);
      s += __shfl_xor(s, 8);  s += __shfl_xor(s, 16); s += __shfl_xor(s, 32);
      float xt = xv_pre * wbuf[tid] * fast_rcp(s);
      float xo = __shfl_xor(xt, 1);
      if (!(tid & 1)) xh_pk[tid >> 1] = pack2(xt, xo);
    }
    lds_barrier();

    // ---- Phase E: gates = bsum + Wcat·[x_tilde; h], 8-deep dual-bank pipeline ----
    {
      float a0 = bsum_r, a1 = 0.f, a2 = 0.f, a3 = 0.f;
      // g0: consume A(0-7), refill A(16-23)
      ECONS(eA0, 0);  EISS(eA0, 16); ECONS(eA1, 1);  EISS(eA1, 17);
      ECONS(eA2, 2);  EISS(eA2, 18); ECONS(eA3, 3);  EISS(eA3, 19);
      ECONS(eA4, 4);  EISS(eA4, 20); ECONS(eA5, 5);  EISS(eA5, 21);
      ECONS(eA6, 6);  EISS(eA6, 22); ECONS(eA7, 7);  EISS(eA7, 23);
      __builtin_amdgcn_sched_barrier(0);
      // g1: consume B(8-15), refill B(24-31)
      ECONS(eB0, 8);  EISS(eB0, 24); ECONS(eB1, 9);  EISS(eB1, 25);
      ECONS(eB2, 10); EISS(eB2, 26); ECONS(eB3, 11); EISS(eB3, 27);
      ECONS(eB4, 12); EISS(eB4, 28); ECONS(eB5, 13); EISS(eB5, 29);
      ECONS(eB6, 14); EISS(eB6, 30); ECONS(eB7, 15); EISS(eB7, 31);
      __builtin_amdgcn_sched_barrier(0);
      // g2: consume A(16-23), refill A(32-39)
      ECONS(eA0, 16); EISS(eA0, 32); ECONS(eA1, 17); EISS(eA1, 33);
      ECONS(eA2, 18); EISS(eA2, 34); ECONS(eA3, 19); EISS(eA3, 35);
      ECONS(eA4, 20); EISS(eA4, 36); ECONS(eA5, 21); EISS(eA5, 37);
      ECONS(eA6, 22); EISS(eA6, 38); ECONS(eA7, 23); EISS(eA7, 39);
      __builtin_amdgcn_sched_barrier(0);
      // g3: consume B(24-31), refill B(40-47)
      ECONS(eB0, 24); EISS(eB0, 40); ECONS(eB1, 25); EISS(eB1, 41);
      ECONS(eB2, 26); EISS(eB2, 42); ECONS(eB3, 27); EISS(eB3, 43);
      ECONS(eB4, 28); EISS(eB4, 44); ECONS(eB5, 29); EISS(eB5, 45);
      ECONS(eB6, 30); EISS(eB6, 46); ECONS(eB7, 31); EISS(eB7, 47);
      __builtin_amdgcn_sched_barrier(0);
      // g4: consume A(32-39), refill A(48-55)
      ECONS(eA0, 32); EISS(eA0, 48); ECONS(eA1, 33); EISS(eA1, 49);
      ECONS(eA2, 34); EISS(eA2, 50); ECONS(eA3, 35); EISS(eA3, 51);
      ECONS(eA4, 36); EISS(eA4, 52); ECONS(eA5, 37); EISS(eA5, 53);
      ECONS(eA6, 38); EISS(eA6, 54); ECONS(eA7, 39); EISS(eA7, 55);
      __builtin_amdgcn_sched_barrier(0);
      // g5: consume B(40-47), refill B(56-63)
      ECONS(eB0, 40); EISS(eB0, 56); ECONS(eB1, 41); EISS(eB1, 57);
      ECONS(eB2, 42); EISS(eB2, 58); ECONS(eB3, 43); EISS(eB3, 59);
      ECONS(eB4, 44); EISS(eB4, 60); ECONS(eB5, 45); EISS(eB5, 61);
      ECONS(eB6, 46); EISS(eB6, 62); ECONS(eB7, 47); EISS(eB7, 63);
      __builtin_amdgcn_sched_barrier(0);
      // g6: consume A(48-55)
      ECONS(eA0, 48); ECONS(eA1, 49); ECONS(eA2, 50); ECONS(eA3, 51);
      ECONS(eA4, 52); ECONS(eA5, 53); ECONS(eA6, 54); ECONS(eA7, 55);
      // g7: consume B(56-63)
      ECONS(eB0, 56); ECONS(eB1, 57); ECONS(eB2, 58); ECONS(eB3, 59);
      ECONS(eB4, 60); ECONS(eB5, 61); ECONS(eB6, 62); ECONS(eB7, 63);
      gbuf[tid] = (a0 + a1) + (a2 + a3);
    }
    lds_barrier();

    // ---- Phase F: LSTM cell update + output + pack h,c ----
    if (tid < 256) {
      float gi = gbuf[tid], gf = gbuf[tid + 256], gg = gbuf[tid + 512], go = gbuf[tid + 768];
      float si = fast_rcp(1.f + fast_exp2(-KLOG2E * gi));
      float sf = fast_rcp(1.f + fast_exp2(-KLOG2E * gf));
      float so = fast_rcp(1.f + fast_exp2(-KLOG2E * go));
      float tg = fmaf(-2.f, fast_rcp(1.f + fast_exp2(KCONST * gg)), 1.f);
      float cn = fmaf(sf, creg, si * tg);
      float tc2 = fmaf(-2.f, fast_rcp(1.f + fast_exp2(KCONST * cn)), 1.f);
      float hn = so * tc2;
      creg = cn;
      float hp = __shfl_xor(hn, 1);
      float cp = __shfl_xor(cn, 1);
      if (!(tid & 1)) {
        uint32_t hpk = pack2(hn, hp);
        uint32_t cpk = pack2(cn, cp);
        hs_pk[tid >> 1] = hpk;
        hs_pk[128 + (tid >> 1)] = cpk;
        xh_pk[128 + (tid >> 1)] = hpk;
      }
      out[(((size_t)t << 7) + (size_t)b) * 256 + tid] = hn;  // out[t][b][m]
    }
    lds_barrier();
  }
}

extern "C" void kernel_launch(void* const* d_in, const int* in_sizes, int n_in,
                              void* d_out, int out_size, void* d_ws, size_t ws_size,
                              hipStream_t stream) {
  const float* X    = (const float*)d_in[0];
  const float* WU_e = (const float*)d_in[1];
  const float* v_e  = (const float*)d_in[2];
  const float* W_ih = (const float*)d_in[3];
  const float* W_hh = (const float*)d_in[4];
  const float* b_ih = (const float*)d_in[5];
  const float* b_hh = (const float*)d_in[6];
  uint8_t* ws = (uint8_t*)d_ws;
  float* out = (float*)d_out;

  (void)hipFuncSetAttribute((const void*)encoder_run,
                            hipFuncAttributeMaxDynamicSharedMemorySize,
                            (int)LDS_TOTAL);

  prep_pack<<<576, 256, 0, stream>>>(WU_e, W_ih, W_hh, ws);
  prep_prex<<<256, 512, 0, stream>>>(X, ws);
  encoder_run<<<NB, 1024, LDS_TOTAL, stream>>>(X, v_e, b_ih, b_hh, ws, out);
}

// Round 7
// 3897.007 us; speedup vs baseline: 2.9043x; 2.6446x over previous
//
#include <hip/hip_runtime.h>
#include <stdint.h>

// Sizes (fixed per reference): B=128, T=256, N=256, M=256
#define NB 128

typedef _Float16 f16;
typedef _Float16 f16x2 __attribute__((ext_vector_type(2)));
typedef uint32_t u32x4 __attribute__((ext_vector_type(4)));

// ---------------- workspace layout (bytes) ----------------
#define WS_PREX   0u            // f16 [128][256][256]  (KC * pre_x[b][n][t'])
#define WS_WUT    16777216u     // uint4[16][1024]: chunk (d8,t') at i*1024 + t'*4 + tq, i=d8&15, tq=d8>>4
#define WS_WCAT   17039360u     // uint4[64][1024]: f16-pairs of concat(W_ih,W_hh)[j][k], chunk (k8,j) at k8*1024+j
#define WS_WXT    18087936u     // f32 [256][256]     WxT[t][t'] = WU_e[t'][512+t]
#define WS_END    18350080u

__device__ __forceinline__ float fast_exp2(float x) {
#if __has_builtin(__builtin_amdgcn_exp2f)
  return __builtin_amdgcn_exp2f(x);
#else
  return exp2f(x);
#endif
}
__device__ __forceinline__ float fast_rcp(float x) {
#if __has_builtin(__builtin_amdgcn_rcpf)
  return __builtin_amdgcn_rcpf(x);
#else
  return 1.0f / x;
#endif
}

__device__ __forceinline__ float fdot2(uint32_t w, uint32_t x, float acc) {
#if __has_builtin(__builtin_amdgcn_fdot2)
  return __builtin_amdgcn_fdot2(__builtin_bit_cast(f16x2, w),
                                __builtin_bit_cast(f16x2, x), acc, false);
#else
  f16x2 a = __builtin_bit_cast(f16x2, w);
  f16x2 b = __builtin_bit_cast(f16x2, x);
  acc = fmaf((float)a.x, (float)b.x, acc);
  acc = fmaf((float)a.y, (float)b.y, acc);
  return acc;
#endif
}

__device__ __forceinline__ uint32_t pack2(float lo, float hi) {
#if __has_builtin(__builtin_amdgcn_cvt_pkrtz)
  return __builtin_bit_cast(uint32_t, __builtin_amdgcn_cvt_pkrtz(lo, hi));
#else
  f16x2 p; p.x = (f16)lo; p.y = (f16)hi;
  return __builtin_bit_cast(uint32_t, p);
#endif
}

// LDS-only barrier: drains LDS ops, leaves global (asm) loads in flight.
__device__ __forceinline__ void lds_barrier() {
  asm volatile("s_waitcnt lgkmcnt(0)" ::: "memory");
  __builtin_amdgcn_s_barrier();
}

// Counted vmem wait + scheduling fence (rule #18: consumers must not hoist).
#define VMW_(N) { asm volatile("s_waitcnt vmcnt(" #N ")" ::: "memory"); \
                  __builtin_amdgcn_sched_barrier(0); }
#define VMW(N) VMW_(N)

// Volatile asm 16B load: issue order = program order, result pinned in VGPRs.
#define GLOAD(R, B, V) \
  asm volatile("global_load_dwordx4 %0, %1, %2" : "=&v"(R) : "v"(V), "s"(B))
// Opaque voffset advance (prevents LICM from materializing 80 invariant addrs).
#define VADV(V) asm volatile("v_add_u32 %0, 0x4000, %0" : "+v"(V))

#define KCONST 2.8853900817779268f  // 2*log2(e)
#define KLOG2E 1.4426950408889634f  // log2(e)

// ---------------- K0: pack/transpose weights ----------------
__global__ __launch_bounds__(256) void prep_pack(const float* __restrict__ WU_e,
                                                 const float* __restrict__ W_ih,
                                                 const float* __restrict__ W_hh,
                                                 uint8_t* __restrict__ ws) {
  float* wxt = (float*)(ws + WS_WXT);
  uint32_t* wut = (uint32_t*)(ws + WS_WUT);
  uint32_t* wcat = (uint32_t*)(ws + WS_WCAT);
  int idx = blockIdx.x * blockDim.x + threadIdx.x;
  if (idx < 65536) {
    int t = idx >> 8, t2 = idx & 255;
    wxt[t * 256 + t2] = WU_e[t2 * 768 + 512 + t];
  } else if (idx < 65536 + 16384) {
    int i2 = idx - 65536;
    int d8 = i2 >> 8, tp = i2 & 255;
    int ii = d8 & 15, tq = d8 >> 4;
    uint32_t* dst = wut + (ii * 1024 + tp * 4 + tq) * 4;
#pragma unroll
    for (int w = 0; w < 4; ++w) {
      int d = d8 * 8 + 2 * w;
      f16x2 p;
      p.x = (f16)WU_e[tp * 768 + d];
      p.y = (f16)WU_e[tp * 768 + d + 1];
      dst[w] = __builtin_bit_cast(uint32_t, p);
    }
  } else if (idx < 65536 + 16384 + 65536) {
    int i2 = idx - (65536 + 16384);
    int k8 = i2 >> 10, j = i2 & 1023;
    uint32_t* dst = wcat + (k8 * 1024 + j) * 4;
#pragma unroll
    for (int w = 0; w < 4; ++w) {
      int k0 = k8 * 8 + 2 * w;
      int k1 = k0 + 1;
      float a = (k0 < 256) ? W_ih[j * 256 + k0] : W_hh[j * 256 + (k0 - 256)];
      float b = (k1 < 256) ? W_ih[j * 256 + k1] : W_hh[j * 256 + (k1 - 256)];
      f16x2 p; p.x = (f16)a; p.y = (f16)b;
      dst[w] = __builtin_bit_cast(uint32_t, p);
    }
  }
}

// ---------------- K1: pre_x[b][n][t'] = KC * sum_t X[b][t][n] * WxT[t][t'] ----------------
__global__ __launch_bounds__(512) void prep_prex(const float* __restrict__ X,
                                                 uint8_t* __restrict__ ws) {
  __shared__ float Xs[32][128];
  __shared__ float Wt[32][256];
  const float* wxt = (const float*)(ws + WS_WXT);
  f16* prex = (f16*)(ws + WS_PREX);
  const int b = blockIdx.x >> 1;
  const int n0 = (blockIdx.x & 1) * 128;
  const int tid = threadIdx.x;
  const int tt = tid & 31;
  const int tn = tid >> 5;
  float acc[8][8];
#pragma unroll
  for (int i = 0; i < 8; ++i)
#pragma unroll
    for (int j = 0; j < 8; ++j) acc[i][j] = 0.f;

  for (int tc = 0; tc < 8; ++tc) {
#pragma unroll
    for (int it = 0; it < 8; ++it) {
      int idx = tid + it * 512;
      int tr = idx >> 7, nc = idx & 127;
      Xs[tr][nc] = X[((b * 256) + tc * 32 + tr) * 256 + n0 + nc];
    }
#pragma unroll
    for (int it = 0; it < 16; ++it) {
      int idx = tid + it * 512;
      int tr = idx >> 8, c = idx & 255;
      Wt[tr][c] = wxt[(tc * 32 + tr) * 256 + c];
    }
    __syncthreads();
    for (int tr = 0; tr < 32; ++tr) {
      float xa[8], wb[8];
#pragma unroll
      for (int i = 0; i < 8; ++i) xa[i] = Xs[tr][tn * 8 + i];
#pragma unroll
      for (int j = 0; j < 8; ++j) wb[j] = Wt[tr][tt * 8 + j];
#pragma unroll
      for (int i = 0; i < 8; ++i)
#pragma unroll
        for (int j = 0; j < 8; ++j) acc[i][j] = fmaf(xa[i], wb[j], acc[i][j]);
    }
    __syncthreads();
  }
#pragma unroll
  for (int i = 0; i < 8; ++i) {
    int n = n0 + tn * 8 + i;
    uint32_t o[4];
#pragma unroll
    for (int u = 0; u < 4; ++u)
      o[u] = pack2(KCONST * acc[i][2 * u], KCONST * acc[i][2 * u + 1]);
    *(uint4*)(prex + (size_t)b * 65536 + n * 256 + tt * 8) = make_uint4(o[0], o[1], o[2], o[3]);
  }
}

// ---------------- K2: persistent recurrence, 1 block per batch element ----------------
// LDS layout (bytes):
#define L_PX    0u       // f16 [256][256] unpadded (512B rows), KC-prescaled
#define L_HSPK  131072u  // u32[280]: f16x2 pairs of [h,c], +8-dword skew per 64-group
#define L_XHPK  132192u  // u32[256]: f16x2 pairs of [x_tilde(128), h(128)]
#define L_KEH   133216u  // f32[288]: KC * e_pre_h, PADDED stride-9
#define L_WB    134368u  // f32[256]: w = exp(e[n])
#define L_GB    135392u  // f32[1024]: gates
#define LDS_TOTAL 139520u

// hs_pk skew: logical j -> physical j + 8*(j>>6). Breaks the 4-way bank
// conflict of Phase A's 4-address read (64*tq mod 32 was 0 for all tq).
#define HSIDX(j) ((j) + (((j) >> 6) << 3))

__global__ __launch_bounds__(1024, 4) void encoder_run(
    const float* __restrict__ X, const float* __restrict__ v_e,
    const float* __restrict__ b_ih, const float* __restrict__ b_hh,
    const uint8_t* __restrict__ ws, float* __restrict__ out) {
  extern __shared__ uint8_t lds[];
  uint32_t* hs_pk = (uint32_t*)(lds + L_HSPK);
  uint32_t* xh_pk = (uint32_t*)(lds + L_XHPK);
  float* keh  = (float*)(lds + L_KEH);
  float* wbuf = (float*)(lds + L_WB);
  float* gbuf = (float*)(lds + L_GB);

  const int b = blockIdx.x;
  const int tid = threadIdx.x;
  const uint8_t* wutb  = ws + WS_WUT;
  const uint8_t* wcatb = ws + WS_WCAT;
  const uint32_t* prex_g = (const uint32_t*)(ws + WS_PREX) + (size_t)b * 32768u;

  const int tq  = tid & 3;        // Phase A: K-quarter
  const int thi = tid >> 2;       // Phase A: t'
  const int li  = tid & 31;       // Phase B: 16B chunk within row
  const int half = (tid >> 5) & 1;
  const int wbase = (tid >> 6) * 16;  // Phase B: first row of this wave
  const uint32_t tid16 = (uint32_t)tid * 16u;

  // ---- init ----
  if (tid < 256) { hs_pk[HSIDX(tid)] = 0u; xh_pk[tid] = 0u; }
  float creg = 0.f;
  float bsum_r = b_ih[tid] + b_hh[tid];
#pragma unroll
  for (int it = 0; it < 8; ++it) {   // copy KC*pre_x[b] into LDS, 8192 x 16B contiguous
    int c = tid + it * 1024;
    uint4 v = *(const uint4*)(prex_g + c * 4);
    *(uint4*)(lds + (size_t)c * 16) = v;
  }
  float m2ve[8], ve_ssum = 0.f;
  {
    float4 v0 = *(const float4*)(v_e + li * 8);
    float4 v1 = *(const float4*)(v_e + li * 8 + 4);
    float vv[8] = {v0.x, v0.y, v0.z, v0.w, v1.x, v1.y, v1.z, v1.w};
#pragma unroll
    for (int j = 0; j < 8; ++j) { m2ve[j] = -2.f * vv[j]; ve_ssum += vv[j]; }
  }
  __syncthreads();   // init only: full drain (vmcnt=0 at loop entry)

#define HVLD(I) (*(const uint4*)(hs_pk + ((((tq << 4) + (I)) << 2) + (tq << 3))))
#define XVLD(I) (*(const uint4*)(xh_pk + ((I) << 2)))
#define ACON(W, HQ) { a = fdot2((W).x, (HQ).x, a); a = fdot2((W).y, (HQ).y, a); \
                      a = fdot2((W).z, (HQ).z, a); a = fdot2((W).w, (HQ).w, a); }
#define ECON(W, XQ) { a0 = fdot2((W).x, (XQ).x, a0); a1 = fdot2((W).y, (XQ).y, a1); \
                      a2 = fdot2((W).z, (XQ).z, a2); a3 = fdot2((W).w, (XQ).w, a3); }
#define EST(R, XQ, KNXT) { VMW(7); ECON(R, XQ); XQ = XVLD(KNXT); \
                           GLOAD(R, wcatb, vc); VADV(vc); }
#define EBLK(B0) \
  EST(e0, xq0, (B0)+2); EST(e1, xq1, (B0)+3); EST(e2, xq0, (B0)+4); EST(e3, xq1, (B0)+5); \
  EST(e4, xq0, (B0)+6); EST(e5, xq1, (B0)+7); EST(e6, xq0, (B0)+8); EST(e7, xq1, (B0)+9);

  for (int t = 0; t < 256; ++t) {
    // ---- issue: X row (oldest), then 16 wut chunks ----
    uint32_t xw;
    {
      uint32_t xoff = (uint32_t)b * 262144u + (uint32_t)t * 1024u + (uint32_t)(tid & 255) * 4u;
      asm volatile("global_load_dword %0, %1, %2" : "=&v"(xw) : "v"(xoff), "s"(X));
    }
    u32x4 w0, w1, w2, w3, w4, w5, w6, w7, w8, w9, w10, w11, w12, w13, w14, w15;
    uint32_t va = tid16;
    GLOAD(w0, wutb, va);  VADV(va); GLOAD(w1, wutb, va);  VADV(va);
    GLOAD(w2, wutb, va);  VADV(va); GLOAD(w3, wutb, va);  VADV(va);
    GLOAD(w4, wutb, va);  VADV(va); GLOAD(w5, wutb, va);  VADV(va);
    GLOAD(w6, wutb, va);  VADV(va); GLOAD(w7, wutb, va);  VADV(va);
    GLOAD(w8, wutb, va);  VADV(va); GLOAD(w9, wutb, va);  VADV(va);
    GLOAD(w10, wutb, va); VADV(va); GLOAD(w11, wutb, va); VADV(va);
    GLOAD(w12, wutb, va); VADV(va); GLOAD(w13, wutb, va); VADV(va);
    GLOAD(w14, wutb, va); VADV(va); GLOAD(w15, wutb, va);

    // ---- Phase A: keh[t'] = KC * sum_d hs[d]*WU_e[t'][d], counted drains ----
    {
      float a = 0.f;
      uint4 hq0 = HVLD(0), hq1 = HVLD(1);
      VMW(15); ACON(w0, hq0);  hq0 = HVLD(2);
      VMW(14); ACON(w1, hq1);  hq1 = HVLD(3);
      VMW(13); ACON(w2, hq0);  hq0 = HVLD(4);
      VMW(12); ACON(w3, hq1);  hq1 = HVLD(5);
      VMW(11); ACON(w4, hq0);  hq0 = HVLD(6);
      VMW(10); ACON(w5, hq1);  hq1 = HVLD(7);
      VMW(9);  ACON(w6, hq0);  hq0 = HVLD(8);
      VMW(8);  ACON(w7, hq1);  hq1 = HVLD(9);
      VMW(7);  ACON(w8, hq0);  hq0 = HVLD(10);
      VMW(6);  ACON(w9, hq1);  hq1 = HVLD(11);
      VMW(5);  ACON(w10, hq0); hq0 = HVLD(12);
      VMW(4);  ACON(w11, hq1); hq1 = HVLD(13);
      VMW(3);  ACON(w12, hq0); hq0 = HVLD(14);
      VMW(2);  ACON(w13, hq1); hq1 = HVLD(15);
      VMW(1);  ACON(w14, hq0);
      VMW(0);  ACON(w15, hq1);
      a += __shfl_xor(a, 1);
      a += __shfl_xor(a, 2);
      if (tq == 0) keh[thi + (thi >> 3)] = KCONST * a;   // padded stride-9
    }

    // ---- issue first 8 wcat chunks (stream during Phase B/C) ----
    u32x4 e0, e1, e2, e3, e4, e5, e6, e7;
    uint32_t vc = tid16;
    GLOAD(e0, wcatb, vc); VADV(vc); GLOAD(e1, wcatb, vc); VADV(vc);
    GLOAD(e2, wcatb, vc); VADV(vc); GLOAD(e3, wcatb, vc); VADV(vc);
    GLOAD(e4, wcatb, vc); VADV(vc); GLOAD(e5, wcatb, vc); VADV(vc);
    GLOAD(e6, wcatb, vc); VADV(vc); GLOAD(e7, wcatb, vc); VADV(vc);

    lds_barrier();

    // ---- Phase B: e[n] = sum_t' ve[t']*tanh(px + eh); wbuf[n] = exp(e[n]) ----
    {
      float kr[8];
      {
        const float* kehb = keh + li * 9;
#pragma unroll
        for (int j = 0; j < 8; ++j) kr[j] = kehb[j];
      }
#pragma unroll
      for (int i = 0; i < 8; ++i) {
        int r = wbase + i * 2 + half;
        uint4 pv = *(const uint4*)(lds + (size_t)r * 512 + (size_t)li * 16);
        float acc = ve_ssum;
        uint32_t dw[4] = {pv.x, pv.y, pv.z, pv.w};
#pragma unroll
        for (int u = 0; u < 4; ++u) {
          f16x2 q = __builtin_bit_cast(f16x2, dw[u]);
          {
            float y = (float)q.x + kr[2 * u];
            acc = fmaf(m2ve[2 * u], fast_rcp(fast_exp2(y) + 1.f), acc);
          }
          {
            float y = (float)q.y + kr[2 * u + 1];
            acc = fmaf(m2ve[2 * u + 1], fast_rcp(fast_exp2(y) + 1.f), acc);
          }
        }
        acc += __shfl_xor(acc, 1);
        acc += __shfl_xor(acc, 2);
        acc += __shfl_xor(acc, 4);
        acc += __shfl_xor(acc, 8);
        acc += __shfl_xor(acc, 16);
        if (li == 0) wbuf[r] = fast_exp2(KLOG2E * acc);
      }
    }
    lds_barrier();

    // ---- Phase C: softmax denom + x_tilde (waves 0-3), pack f16 pairs ----
    if (tid < 256) {
      int lane = tid & 63;
      float4 wv = *(const float4*)(wbuf + lane * 4);
      float s = (wv.x + wv.y) + (wv.z + wv.w);
      s += __shfl_xor(s, 1);  s += __shfl_xor(s, 2);  s += __shfl_xor(s, 4);
      s += __shfl_xor(s, 8);  s += __shfl_xor(s, 16); s += __shfl_xor(s, 32);
      float xv_pre = __builtin_bit_cast(float, xw);   // X drained by Phase A's vmcnt(0)
      float xt = xv_pre * wbuf[tid] * fast_rcp(s);
      float xo = __shfl_xor(xt, 1);
      if (!(tid & 1)) xh_pk[tid >> 1] = pack2(xt, xo);
    }
    lds_barrier();

    // ---- Phase E: gates = bsum + Wcat·[x_tilde; h], 8-deep rolling window ----
    {
      float a0 = bsum_r, a1 = 0.f, a2 = 0.f, a3 = 0.f;
      uint4 xq0 = XVLD(0), xq1 = XVLD(1);
      EBLK(0);  EBLK(8);  EBLK(16); EBLK(24);
      EBLK(32); EBLK(40); EBLK(48);
      // tail: chunks 56..63, descending drains
      VMW(7); ECON(e0, xq0); xq0 = XVLD(58);
      VMW(6); ECON(e1, xq1); xq1 = XVLD(59);
      VMW(5); ECON(e2, xq0); xq0 = XVLD(60);
      VMW(4); ECON(e3, xq1); xq1 = XVLD(61);
      VMW(3); ECON(e4, xq0); xq0 = XVLD(62);
      VMW(2); ECON(e5, xq1); xq1 = XVLD(63);
      VMW(1); ECON(e6, xq0);
      VMW(0); ECON(e7, xq1);
      gbuf[tid] = (a0 + a1) + (a2 + a3);
    }
    lds_barrier();

    // ---- Phase F: LSTM cell update + output + pack h,c ----
    if (tid < 256) {
      float gi = gbuf[tid], gf = gbuf[tid + 256], gg = gbuf[tid + 512], go = gbuf[tid + 768];
      float si = fast_rcp(1.f + fast_exp2(-KLOG2E * gi));
      float sf = fast_rcp(1.f + fast_exp2(-KLOG2E * gf));
      float so = fast_rcp(1.f + fast_exp2(-KLOG2E * go));
      float tg = fmaf(-2.f, fast_rcp(1.f + fast_exp2(KCONST * gg)), 1.f);
      float cn = fmaf(sf, creg, si * tg);
      float tc2 = fmaf(-2.f, fast_rcp(1.f + fast_exp2(KCONST * cn)), 1.f);
      float hn = so * tc2;
      creg = cn;
      float hp = __shfl_xor(hn, 1);
      float cp = __shfl_xor(cn, 1);
      if (!(tid & 1)) {
        int j = tid >> 1;
        uint32_t hpk = pack2(hn, hp);
        uint32_t cpk = pack2(cn, cp);
        hs_pk[HSIDX(j)] = hpk;
        hs_pk[HSIDX(128 + j)] = cpk;
        xh_pk[128 + j] = hpk;
      }
      uint32_t ooff = (uint32_t)t * 131072u + (uint32_t)b * 1024u + (uint32_t)tid * 4u;
      asm volatile("global_store_dword %0, %1, %2" :: "v"(ooff), "v"(hn), "s"(out) : "memory");
    }
    lds_barrier();
  }
}

extern "C" void kernel_launch(void* const* d_in, const int* in_sizes, int n_in,
                              void* d_out, int out_size, void* d_ws, size_t ws_size,
                              hipStream_t stream) {
  const float* X    = (const float*)d_in[0];
  const float* WU_e = (const float*)d_in[1];
  const float* v_e  = (const float*)d_in[2];
  const float* W_ih = (const float*)d_in[3];
  const float* W_hh = (const float*)d_in[4];
  const float* b_ih = (const float*)d_in[5];
  const float* b_hh = (const float*)d_in[6];
  uint8_t* ws = (uint8_t*)d_ws;
  float* out = (float*)d_out;

  (void)hipFuncSetAttribute((const void*)encoder_run,
                            hipFuncAttributeMaxDynamicSharedMemorySize,
                            (int)LDS_TOTAL);

  prep_pack<<<576, 256, 0, stream>>>(WU_e, W_ih, W_hh, ws);
  prep_prex<<<256, 512, 0, stream>>>(X, ws);
  encoder_run<<<NB, 1024, LDS_TOTAL, stream>>>(X, v_e, b_ih, b_hh, ws, out);
}